// Round 20
// baseline (62.488 us; speedup 1.0000x reference)
//
#include <hip/hip_runtime.h>
#include <hip/hip_bf16.h>

#define D_ 64
#define HW_ 4096
#define K_ 1024
#define NPTS_ 65536
#define QOUT_ 4194304      // B*D*H*W, offset of idx region in d_out
#define DELTA 0.006f       // ambiguity margin; worst-case bf16-split diff ~2e-3
#define INF_ 3.4e38f

typedef short bf16x8 __attribute__((ext_vector_type(8)));
typedef float f32x4 __attribute__((ext_vector_type(4)));

// ---- pack kernel: cnorm + bf16 hi/lo split of (-2*cb) in MFMA-fragment order ----
// P layout (shorts): [g(64)][frag(4)][lane(64)][8]
//   code j = g*16 + (l&15), dims d = (frag>>1)*32 + (l>>4)*8 + i, lvl = frag&1
__global__ __launch_bounds__(256) void vq_pack(const float* __restrict__ cb,
                                               float* __restrict__ cnorm,
                                               short* __restrict__ P) {
    const int t = blockIdx.x * 256 + threadIdx.x;   // 0..4095
    const int gch = t >> 6, l = t & 63;
    const int j  = gch * 16 + (l & 15);
    const int dg = l >> 4;
#pragma unroll
    for (int s = 0; s < 2; ++s) {
        const float* src = cb + j * D_ + s * 32 + dg * 8;
        short hb[8], lb[8];
#pragma unroll
        for (int i = 0; i < 8; ++i) {
            const float v = -2.f * src[i];
            __hip_bfloat16 h = __float2bfloat16(v);
            hb[i] = *(const short*)&h;
            const float r = v - __bfloat162float(h);
            __hip_bfloat16 lo = __float2bfloat16(r);
            lb[i] = *(const short*)&lo;
        }
        short* dh = P + ((size_t)(gch * 4 + s * 2 + 0) * 64 + l) * 8;
        short* dl = P + ((size_t)(gch * 4 + s * 2 + 1) * 64 + l) * 8;
#pragma unroll
        for (int i = 0; i < 8; ++i) { dh[i] = hb[i]; dl[i] = lb[i]; }
    }
    if (t < K_) {
        const float4* r = (const float4*)(cb + (size_t)t * D_);
        float s0 = 0.f, s1 = 0.f, s2 = 0.f, s3 = 0.f;
#pragma unroll
        for (int i = 0; i < 16; ++i) {
            float4 v = r[i];
            s0 = fmaf(v.x, v.x, s0); s1 = fmaf(v.y, v.y, s1);
            s2 = fmaf(v.z, v.z, s2); s3 = fmaf(v.w, v.w, s3);
        }
        cnorm[t] = (s0 + s1) + (s2 + s3);
    }
}

// one 16-code group step: 12 MFMAs (proven chain split) + min-update.
// s_setprio(1) around the MFMA cluster: barrier-free waves sit at different
// groups -> CU scheduler can favor the MFMA-entering wave (T5 prereq holds).
#define VQ_STEP(BH0, BL0, BH1, BL1, CN, G) do {                                   \
    const int kc_ = (G) * 16 + kl;                                                \
    f32x4 a0a = {0.f,0.f,0.f,0.f}, a0b = {0.f,0.f,0.f,0.f};                       \
    f32x4 a1a = {0.f,0.f,0.f,0.f}, a1b = {0.f,0.f,0.f,0.f};                       \
    __builtin_amdgcn_s_setprio(1);                                                \
    a0a = __builtin_amdgcn_mfma_f32_16x16x32_bf16(ah[0][0], BH0, a0a, 0, 0, 0);   \
    a1a = __builtin_amdgcn_mfma_f32_16x16x32_bf16(ah[1][0], BH0, a1a, 0, 0, 0);   \
    a0b = __builtin_amdgcn_mfma_f32_16x16x32_bf16(ah[0][1], BH1, a0b, 0, 0, 0);   \
    a1b = __builtin_amdgcn_mfma_f32_16x16x32_bf16(ah[1][1], BH1, a1b, 0, 0, 0);   \
    a0a = __builtin_amdgcn_mfma_f32_16x16x32_bf16(al[0][0], BH0, a0a, 0, 0, 0);   \
    a1a = __builtin_amdgcn_mfma_f32_16x16x32_bf16(al[1][0], BH0, a1a, 0, 0, 0);   \
    a0b = __builtin_amdgcn_mfma_f32_16x16x32_bf16(al[0][1], BH1, a0b, 0, 0, 0);   \
    a1b = __builtin_amdgcn_mfma_f32_16x16x32_bf16(al[1][1], BH1, a1b, 0, 0, 0);   \
    a0a = __builtin_amdgcn_mfma_f32_16x16x32_bf16(ah[0][0], BL0, a0a, 0, 0, 0);   \
    a1a = __builtin_amdgcn_mfma_f32_16x16x32_bf16(ah[1][0], BL0, a1a, 0, 0, 0);   \
    a0b = __builtin_amdgcn_mfma_f32_16x16x32_bf16(ah[0][1], BL1, a0b, 0, 0, 0);   \
    a1b = __builtin_amdgcn_mfma_f32_16x16x32_bf16(ah[1][1], BL1, a1b, 0, 0, 0);   \
    __builtin_amdgcn_s_setprio(0);                                                \
    _Pragma("unroll")                                                             \
    for (int t_ = 0; t_ < 2; ++t_)                                                \
        _Pragma("unroll")                                                         \
        for (int r_ = 0; r_ < 4; ++r_) {                                          \
            const int q_ = t_ * 4 + r_;                                           \
            const float d2_ = (CN) + ((t_ == 0) ? (a0a[r_] + a0b[r_])             \
                                                : (a1a[r_] + a1b[r_]));           \
            const bool lt_ = d2_ < m1[q_];                                        \
            m2[q_] = fminf(m2[q_], fmaxf(m1[q_], d2_));                           \
            m1[q_] = fminf(m1[q_], d2_);                                          \
            i1[q_] = lt_ ? kc_ : i1[q_];                                          \
        }                                                                         \
} while (0)

#define LOAD_SET(R0, R1, R2, R3, CN, G) do {                                      \
    R0 = gp[((G) * 4 + 0) * 64 + lane];                                           \
    R1 = gp[((G) * 4 + 1) * 64 + lane];                                           \
    R2 = gp[((G) * 4 + 2) * 64 + lane];                                           \
    R3 = gp[((G) * 4 + 3) * 64 + lane];                                           \
    CN = cnorm_g[(G) * 16 + kl];                                                  \
} while (0)

// ---- fused main: 3-deep register-pipelined global-B streaming ----
// 512 blocks x 256 thr (4 waves x 32 pts). Barrier-free K-loop; three named
// register sets A/B/C rotate: prefetch distance = 2 full groups (~320 cyc)
// > L2 latency (~200-300) -> auto-waitcnt finds data landed (R19's 2-deep
// undershot by ~40-140 cyc/group). (256,2) -> VGPR cap 256.
// Tripwires: VGPR > 200 or WRITE >> 17 MB = spill; absmax != 0 = bug.
__global__ __launch_bounds__(256, 2) void vq_main(const float* __restrict__ x,
                                                  const float* __restrict__ cb,
                                                  const float* __restrict__ cnorm_g,
                                                  const short* __restrict__ P,
                                                  float* __restrict__ out) {
    __shared__ float tile[128 * 65];   // 33.3 KB epilogue transpose staging
    __shared__ int res_idx[128];
    __shared__ int flist[128];
    __shared__ int fcnt;

    const int tid  = threadIdx.x;
    const int lane = tid & 63;
    const int wid  = tid >> 6;        // 0..3 = 32-pt group
    const int kl   = lane & 15;
    const int pg   = blockIdx.x;      // 0..511
    const int bb   = pg >> 5;
    const int hw0  = (pg & 31) << 7;  // 128 pts per block

    if (tid == 0) fcnt = 0;

    // x load + split: wave owns 32 points (two 16x16 A-tiles)
    bf16x8 ah[2][2], al[2][2];
    {
        const float* xb = x + (size_t)bb * (D_ * HW_) + hw0;
#pragma unroll
        for (int t = 0; t < 2; ++t) {
            const int p_l = wid * 32 + t * 16 + kl;
#pragma unroll
            for (int s = 0; s < 2; ++s) {
                const int d0 = s * 32 + (lane >> 4) * 8;
#pragma unroll
                for (int i = 0; i < 8; ++i) {
                    const float v = xb[(size_t)(d0 + i) * HW_ + p_l];
                    __hip_bfloat16 h = __float2bfloat16(v);
                    ah[t][s][i] = *(const short*)&h;
                    const float r = v - __bfloat162float(h);
                    __hip_bfloat16 lo = __float2bfloat16(r);
                    al[t][s][i] = *(const short*)&lo;
                }
            }
        }
    }
    __syncthreads();   // fcnt visible before flag writes

    float m1[8], m2[8];
    int   i1[8];
#pragma unroll
    for (int q = 0; q < 8; ++q) { m1[q] = INF_; m2[q] = INF_; i1[q] = 0; }

    const bf16x8* gp = (const bf16x8*)P;

    // prologue: groups 0,1,2 -> A,B,C register sets
    bf16x8 A0, A1, A2, A3, B0, B1, B2, B3, C0, C1, C2, C3;
    float cnA, cnB, cnC;
    LOAD_SET(A0, A1, A2, A3, cnA, 0);
    LOAD_SET(B0, B1, B2, B3, cnB, 1);
    LOAD_SET(C0, C1, C2, C3, cnC, 2);

    // 21 iterations x 3 groups = groups 0..62; group 63 in epilogue.
#pragma unroll 1
    for (int t3 = 0; t3 < 21; ++t3) {
        const int g = t3 * 3;
        VQ_STEP(A0, A1, A2, A3, cnA, g);
        LOAD_SET(A0, A1, A2, A3, cnA, g + 3);           // g+3 <= 63 always
        VQ_STEP(B0, B1, B2, B3, cnB, g + 1);
        if (g + 4 < 64) LOAD_SET(B0, B1, B2, B3, cnB, g + 4);
        VQ_STEP(C0, C1, C2, C3, cnC, g + 2);
        if (g + 5 < 64) LOAD_SET(C0, C1, C2, C3, cnC, g + 5);
    }
    VQ_STEP(A0, A1, A2, A3, cnA, 63);   // final group

    // cross-lane (m1,i1,m2) reduce over the 16 lanes sharing (lane>>4);
    // wave covered all K -> result final.
#pragma unroll
    for (int q = 0; q < 8; ++q) {
        float a1 = m1[q], a2 = m2[q];
        int   ai = i1[q];
#pragma unroll
        for (int m = 1; m < 16; m <<= 1) {
            const float o1 = __shfl_xor(a1, m);
            const int   oi = __shfl_xor(ai, m);
            const float o2 = __shfl_xor(a2, m);
            const float nm2 = fminf(fminf(a2, o2), fmaxf(a1, o1));
            if (o1 < a1 || (o1 == a1 && oi < ai)) { a1 = o1; ai = oi; }
            a2 = nm2;
        }
        if ((lane & 15) == 0) {
            const int t = q >> 2, r = q & 3;
            const int pt = wid * 32 + t * 16 + 4 * (lane >> 4) + r;
            res_idx[pt] = ai;
            if (a2 - a1 <= DELTA) { const int p = atomicAdd(&fcnt, 1); flist[p] = pt; }
        }
    }
    __syncthreads();

    // exact fp32 rescan for ambiguous points (expected ~0.1/block)
    const int nf = fcnt;
    for (int i = wid; i < nf; i += 4) {
        const int pt = flist[i];
        const float* xr = x + (size_t)bb * (D_ * HW_) + hw0 + pt;
        float xv[D_];
#pragma unroll
        for (int d = 0; d < D_; ++d) xv[d] = xr[(size_t)d * HW_];   // wave-uniform
        float b1 = INF_; int bi = 0;
        for (int cc = 0; cc < 16; ++cc) {
            const int row = lane * 16 + cc;
            const float4* cr = (const float4*)(cb + (size_t)row * D_);
            float a0 = 0.f, a1 = 0.f, a2 = 0.f, a3 = 0.f;
#pragma unroll
            for (int g = 0; g < 16; ++g) {
                const float4 cf = cr[g];
                a0 = fmaf(xv[4 * g + 0], cf.x, a0);
                a1 = fmaf(xv[4 * g + 1], cf.y, a1);
                a2 = fmaf(xv[4 * g + 2], cf.z, a2);
                a3 = fmaf(xv[4 * g + 3], cf.w, a3);
            }
            const float dot = (a0 + a1) + (a2 + a3);
            const float d2 = fmaf(-2.f, dot, cnorm_g[row]);
            if (d2 < b1) { b1 = d2; bi = row; }
        }
#pragma unroll
        for (int m = 1; m < 64; m <<= 1) {
            const float o1 = __shfl_xor(b1, m);
            const int   oi = __shfl_xor(bi, m);
            if (o1 < b1 || (o1 == b1 && oi < bi)) { b1 = o1; bi = oi; }
        }
        if (lane == 0) res_idx[pt] = bi;
    }
    __syncthreads();

    // idx output (float; exact for values <= 1023)
    if (tid < 128) out[(size_t)QOUT_ + pg * 128 + tid] = (float)res_idx[tid];

    // Phase A: gather winning rows (16 lanes x 16 B = full 256 B row each),
    // write into [pt][65] tile. Banks: pt + 4dq + j -> 2-way max (free).
#pragma unroll
    for (int pass = 0; pass < 8; ++pass) {
        const int pt = pass * 16 + (tid >> 4);
        const int dq = tid & 15;
        const float4 v = *(const float4*)(cb + (size_t)res_idx[pt] * D_ + dq * 4);
        tile[pt * 65 + dq * 4 + 0] = v.x;
        tile[pt * 65 + dq * 4 + 1] = v.y;
        tile[pt * 65 + dq * 4 + 2] = v.z;
        tile[pt * 65 + dq * 4 + 3] = v.w;
    }
    __syncthreads();

    // Phase B: 4 scalar tile reads -> one float4 store (512 B contiguous per d)
    float* ob = out + (size_t)bb * (D_ * HW_) + hw0;
#pragma unroll
    for (int it = 0; it < 8; ++it) {
        const int e = it * 256 + tid;   // 0..2047
        const int d = e >> 5;           // 0..63
        const int g = e & 31;           // float4 group within 128 pts
        float4 q;
        q.x = tile[(g * 4 + 0) * 65 + d];
        q.y = tile[(g * 4 + 1) * 65 + d];
        q.z = tile[(g * 4 + 2) * 65 + d];
        q.w = tile[(g * 4 + 3) * 65 + d];
        *(float4*)(ob + (size_t)d * HW_ + g * 4) = q;
    }
}

extern "C" void kernel_launch(void* const* d_in, const int* in_sizes, int n_in,
                              void* d_out, int out_size, void* d_ws, size_t ws_size,
                              hipStream_t stream) {
    const float* x  = (const float*)d_in[0];   // (16, 64, 64, 64)
    const float* cb = (const float*)d_in[1];   // (1024, 64)
    float* out   = (float*)d_out;
    float* cnorm = (float*)d_ws;                       // 4 KB
    short* P     = (short*)((char*)d_ws + 4096);       // 256 KB packed bf16 codebook

    vq_pack<<<16, 256, 0, stream>>>(cb, cnorm, P);
    vq_main<<<NPTS_ / 128, 256, 0, stream>>>(x, cb, cnorm, P, out);
}